// Round 12
// baseline (342.317 us; speedup 1.0000x reference)
//
#include <hip/hip_runtime.h>
#include <math.h>

#define BUCKET_SHIFT 8  // 256 nodes per bucket
#define MAX_BE 832      // max staged edges per block (block edge count ~ Poisson(512), 14 sigma)
#define CHUNK 4096      // edges per CSR-build chunk (391 blocks: better CU coverage)
#define GSTRIDE 48      // Gn/Gs row stride (47 cols used; 96 B rows, -25% vs 64)
#define BCAP 4608       // fixed per-bucket edge capacity (mean 4096, +8 sigma)

typedef short s8v __attribute__((ext_vector_type(8)));   // 8 bf16 (4 VGPRs)
typedef float f4v __attribute__((ext_vector_type(4)));   // 4 fp32 acc
typedef unsigned short u16;

__device__ inline u16 f2bf(float f) {  // RNE fp32->bf16
    unsigned u = __float_as_uint(f);
    return (u16)((u + 0x7FFFu + ((u >> 16) & 1u)) >> 16);
}
__device__ inline float bf2f(u16 s) { return __uint_as_float(((unsigned)s) << 16); }
__device__ inline float blo(unsigned v) { return __uint_as_float(v << 16); }
__device__ inline float bhi(unsigned v) { return __uint_as_float(v & 0xffff0000u); }

// ---------------- CSR build (bucketed, fixed-capacity: no count/scan passes) ----------------
// Bucket j owns interm/ssrc region [j*BCAP, (j+1)*BCAP). The region's tail above the
// bucket's true edge count is UNINITIALIZED — every consumer must clamp row ends with
// bend = j*BCAP + min(gcnt[j], BCAP). (R5 crash: rowptr[n+1] of a bucket's last node
// points at the NEXT bucket's base; unclamped loops walked the gap -> OOB gather.)

// Merged dispatch 1: scatter + weight-pack + x->bf16 convert (mutually independent;
// scatter's 391 blocks underfill the 256-CU machine, convert's 6250 streaming blocks
// fill it — R12 re-balance so build-only runs as the short second dispatch).
// Block ranges: [0, nChunks) scatter | [nChunks, +320) pack | [nChunks+320, +conv) convert.
__global__ __launch_bounds__(256) void scatter_fat_kernel(
    const int* __restrict__ src, const int* __restrict__ dst,
    int* __restrict__ gcursor, unsigned* __restrict__ interm, int n_edges, int nbuckets,
    const float* __restrict__ x, u16* __restrict__ xb, long total8,
    const float* __restrict__ Wl0, const float* __restrict__ Wr0,
    const float* __restrict__ Wl1, const float* __restrict__ Wr1,
    const float* __restrict__ Wl2, const float* __restrict__ Wr2,
    u16* __restrict__ wf0, u16* __restrict__ wf1, u16* __restrict__ wf2,
    int nChunks) {
    int blk = blockIdx.x;
    int tid = threadIdx.x;

    if (blk < nChunks) {
        // ---- scatter: per-chunk LDS histogram -> per-bucket reservation -> write interm
        __shared__ int hist[512];
        __shared__ int gbase[512];
        for (int j = tid; j < nbuckets; j += 256) hist[j] = 0;
        __syncthreads();
        int e0 = blk * CHUNK;
        int e1 = min(e0 + CHUNK, n_edges);
        for (int e = e0 + tid; e < e1; e += 256)
            atomicAdd(&hist[dst[e] >> BUCKET_SHIFT], 1);
        __syncthreads();
        for (int j = tid; j < nbuckets; j += 256) {
            int c = hist[j];
            gbase[j] = j * BCAP + (c > 0 ? atomicAdd(&gcursor[j], c) : 0);
            hist[j] = 0;
        }
        __syncthreads();
        for (int e = e0 + tid; e < e1; e += 256) {
            int d = dst[e];
            int s = src[e];
            int j = d >> BUCKET_SHIFT;
            int p = atomicAdd(&hist[j], 1);
            int idx = gbase[j] + p;
            if (idx < (j + 1) * BCAP)  // 8-sigma safety: never cross into next bucket
                interm[idx] = ((unsigned)s << 8) | (unsigned)(d & 255);
        }
    } else if (blk < nChunks + 320) {
        // ---- pack: weights -> MFMA fragment order
        int b = blk - nChunks;  // 0..319
        if (b < 256) {
            const float* Wl = (b < 128) ? Wl0 : Wl1;
            const float* Wr = (b < 128) ? Wr0 : Wr1;
            u16* outw = (b < 128) ? wf0 : wf1;
            int idx = (b & 127) * 256 + tid;  // 256*128
            int k = idx >> 7, c = idx & 127;
            float v = (k < 128) ? Wl[k * 128 + c] : Wr[(k - 128) * 128 + c];
            int kt = k >> 5, q = (k >> 3) & 3, j = k & 7, ct = c >> 4, n = c & 15;
            outw[(((kt * 8 + ct) * 64 + q * 16 + n) << 3) + j] = f2bf(v);
        } else {
            int idx = (b - 256) * 256 + tid;  // 128*128
            int k = idx >> 7, c = idx & 127;
            float v = 0.f;
            if (c < 47) v = Wl2[k * 47 + c];
            else if (c >= 64 && c < 111) v = Wr2[k * 47 + (c - 64)];
            int kt = k >> 5, q = (k >> 3) & 3, j = k & 7, ct = c >> 4, n = c & 15;
            wf2[(((kt * 8 + ct) * 64 + q * 16 + n) << 3) + j] = f2bf(v);
        }
    } else {
        // ---- convert: x (fp32) -> xb (bf16), 8 elems/thread
        long i = (long)(blk - nChunks - 320) * 256 + tid;
        if (i >= total8) return;
        const float* p = &x[i * 8];
        float4 lo = *(const float4*)p;
        float4 hi = *(const float4*)(p + 4);
        union { u16 u[8]; s8v v; } t;
        t.u[0] = f2bf(lo.x); t.u[1] = f2bf(lo.y); t.u[2] = f2bf(lo.z); t.u[3] = f2bf(lo.w);
        t.u[4] = f2bf(hi.x); t.u[5] = f2bf(hi.y); t.u[6] = f2bf(hi.z); t.u[7] = f2bf(hi.w);
        *(s8v*)&xb[i * 8] = t.v;
    }
}

// Dispatch 2: bucket_build — per-node counts (LDS) -> block scan -> rowptr/invd -> ssrc.
__global__ __launch_bounds__(256) void bucket_build_kernel(const unsigned* __restrict__ interm,
                                                           const int* __restrict__ gcursor,
                                                           int* __restrict__ rowptr,
                                                           float* __restrict__ invd,
                                                           int* __restrict__ ssrc, int n_nodes) {
    __shared__ int cnt[256];
    __shared__ int cur[256];
    __shared__ int wsum[4], woff[4];
    int tid = threadIdx.x;
    int nb0 = blockIdx.x << BUCKET_SHIFT;
    int base = blockIdx.x * BCAP;
    int end = base + min(gcursor[blockIdx.x], BCAP);
    cnt[tid] = 0;
    __syncthreads();
    for (int e = base + tid; e < end; e += 256)
        atomicAdd(&cnt[interm[e] & 255u], 1);
    __syncthreads();
    int c = cnt[tid];
    int lane = tid & 63, wave = tid >> 6;
    int v = c;
#pragma unroll
    for (int off = 1; off < 64; off <<= 1) {
        int t = __shfl_up(v, off, 64);
        if (lane >= off) v += t;
    }
    if (lane == 63) wsum[wave] = v;
    __syncthreads();
    if (tid == 0) {
        int run = 0;
#pragma unroll
        for (int w = 0; w < 4; ++w) { woff[w] = run; run += wsum[w]; }
    }
    __syncthreads();
    int excl = woff[wave] + (v - c);
    int node = nb0 + tid;
    if (node < n_nodes) {
        rowptr[node] = base + excl;
        invd[node] = c > 0 ? 1.0f / (float)c : 0.0f;
        if (node == n_nodes - 1) rowptr[n_nodes] = base + excl + c;
    }
    cur[tid] = base + excl;
    __syncthreads();
    for (int e = base + tid; e < end; e += 256) {
        unsigned p = interm[e];
        int pos = atomicAdd(&cur[p & 255u], 1);
        ssrc[pos] = (int)(p >> 8);
    }
}

// ---------------- fused SAGE layer: LDS edge staging -> gather-agg -> MFMA ----------------
// Gather: 32-lane groups pull row indices from an LDS atomic counter. Per row: 32
// lanes x uint2 (8 B) = one full 256 B feature row per load instruction, 8 edges
// unrolled (4 KB in flight / wave).
// R2 lesson: do NOT split lanes across multiple edges — more concurrent unique rows
// thrashes L2 (FETCH +23%, WRITE 4x).
// R5 lesson: bucket-strided ssrc has an uninitialized gap at each bucket tail; all
// row ends MUST be clamped to bend.
// R9 lesson: KEEP eloc LDS index staging — breaks the idx-load -> gather-load chain.
// R12: self-row staging is async-split (T14): loads issued into registers right AFTER
// the eloc barrier (a barrier would drain vmcnt), As write after the gather loop —
// 25.6 MB of streaming reads hide under the gather latency.
// LDS: As 16896 B + eloc 3328 B + rp 132 B + rowctr -> 20480 -> 8 blocks/CU.
#define SAGE_PROLOGUE()                                                                   \
    __shared__ u16 As[32][264];                                                           \
    __shared__ int eloc[MAX_BE];                                                          \
    __shared__ int rp[33];                                                                \
    __shared__ int rowctr;                                                                \
    int tid = threadIdx.x;                                                                \
    int n0 = blockIdx.x * 32;                                                             \
    if (tid < 33) rp[tid] = rowptr[min(n0 + tid, n_nodes)];                               \
    if (tid == 0) rowctr = 0;                                                             \
    __syncthreads();                                                                      \
    int bkt = n0 >> BUCKET_SHIFT;                                                         \
    int bend = bkt * BCAP + min(gcnt[bkt], BCAP);                                         \
    int base = rp[0];                                                                     \
    int nE = min(rp[32], bend) - base;                                                    \
    bool staged = nE <= MAX_BE;                                                           \
    if (staged) {                                                                         \
        for (int i = tid; i < nE; i += 256) eloc[i] = ssrc[base + i];                     \
    }                                                                                     \
    __syncthreads();                                                                      \
    const u16* hin = (const u16*)hin2;                                                    \
    s8v self0 = (s8v){0, 0, 0, 0, 0, 0, 0, 0}, self1 = self0;                             \
    {                                                                                     \
        int nn0 = n0 + (tid >> 4);                                                        \
        int nn1 = n0 + ((tid + 256) >> 4);                                                \
        int c8 = (tid & 15) * 8;                                                          \
        if (nn0 < n_nodes) self0 = *(const s8v*)&hin[(size_t)nn0 * 128 + c8];             \
        if (nn1 < n_nodes) self1 = *(const s8v*)&hin[(size_t)nn1 * 128 + c8];             \
    }                                                                                     \
    int d = tid & 31;                                                                     \
    while (true) {                                                                        \
        int row = 0;                                                                      \
        if (d == 0) row = atomicAdd(&rowctr, 1);                                          \
        row = __shfl(row, 0, 32);                                                         \
        if (row >= 32) break;                                                             \
        int n = n0 + row;                                                                 \
        float a0 = 0.f, a1 = 0.f, a2 = 0.f, a3 = 0.f;                                     \
        int e = rp[row] - base, e1 = min(rp[row + 1], bend) - base;                       \
        if (staged) {                                                                     \
            for (; e + 7 < e1; e += 8) {                                                  \
                int s[8];                                                                 \
                _Pragma("unroll")                                                         \
                for (int j = 0; j < 8; ++j) s[j] = eloc[e + j];                           \
                uint2 vv[8];                                                              \
                _Pragma("unroll")                                                         \
                for (int j = 0; j < 8; ++j) vv[j] = hin2[(size_t)s[j] * 32 + d];          \
                _Pragma("unroll")                                                         \
                for (int j = 0; j < 8; ++j) {                                             \
                    a0 += blo(vv[j].x); a1 += bhi(vv[j].x);                               \
                    a2 += blo(vv[j].y); a3 += bhi(vv[j].y);                               \
                }                                                                         \
            }                                                                             \
            for (; e < e1; ++e) {                                                         \
                uint2 vv = hin2[(size_t)eloc[e] * 32 + d];                                \
                a0 += blo(vv.x); a1 += bhi(vv.x);                                         \
                a2 += blo(vv.y); a3 += bhi(vv.y);                                         \
            }                                                                             \
        } else {                                                                          \
            for (; e + 7 < e1; e += 8) {                                                  \
                int s[8];                                                                 \
                _Pragma("unroll")                                                         \
                for (int j = 0; j < 8; ++j) s[j] = ssrc[base + e + j];                    \
                uint2 vv[8];                                                              \
                _Pragma("unroll")                                                         \
                for (int j = 0; j < 8; ++j) vv[j] = hin2[(size_t)s[j] * 32 + d];          \
                _Pragma("unroll")                                                         \
                for (int j = 0; j < 8; ++j) {                                             \
                    a0 += blo(vv[j].x); a1 += bhi(vv[j].x);                               \
                    a2 += blo(vv[j].y); a3 += bhi(vv[j].y);                               \
                }                                                                         \
            }                                                                             \
            for (; e < e1; ++e) {                                                         \
                uint2 vv = hin2[(size_t)ssrc[base + e] * 32 + d];                         \
                a0 += blo(vv.x); a1 += bhi(vv.x);                                         \
                a2 += blo(vv.y); a3 += bhi(vv.y);                                         \
            }                                                                             \
        }                                                                                 \
        float w = (n < n_nodes) ? invd[n] : 0.f;                                          \
        a0 *= w; a1 *= w; a2 *= w; a3 *= w;                                               \
        uint2 o;                                                                          \
        o.x = (unsigned)f2bf(a0) | ((unsigned)f2bf(a1) << 16);                            \
        o.y = (unsigned)f2bf(a2) | ((unsigned)f2bf(a3) << 16);                            \
        *(uint2*)&As[row][d * 4] = o;                                                     \
    }                                                                                     \
    *(s8v*)&As[tid >> 4][128 + (tid & 15) * 8] = self0;                                   \
    *(s8v*)&As[(tid + 256) >> 4][128 + (tid & 15) * 8] = self1;                           \
    __syncthreads();                                                                      \
    int wave = tid >> 6, lane = tid & 63;                                                 \
    int rt = wave & 1, ch = wave >> 1;                                                    \
    int m = lane & 15, q = lane >> 4;                                                     \
    f4v acc[4];                                                                           \
    _Pragma("unroll")                                                                     \
    for (int c = 0; c < 4; ++c) acc[c] = (f4v){0.f, 0.f, 0.f, 0.f};                       \
    _Pragma("unroll")                                                                     \
    for (int kt = 0; kt < 8; ++kt) {                                                      \
        s8v a = *(const s8v*)&As[rt * 16 + m][kt * 32 + q * 8];                           \
        _Pragma("unroll")                                                                 \
        for (int c = 0; c < 4; ++c) {                                                     \
            int ctg = ch * 4 + c;                                                         \
            s8v b = *(const s8v*)&Wfrag[(((size_t)kt * 8 + ctg) * 64 + lane) * 8];        \
            acc[c] = __builtin_amdgcn_mfma_f32_16x16x32_bf16(a, b, acc[c], 0, 0, 0);      \
        }                                                                                 \
    }

// hout = relu([mean_agg(hin) | hin] @ Wfrag + b). hin/hout distinct buffers.
__global__ __launch_bounds__(256, 8) void sage_layer_mfma(const uint2* __restrict__ hin2,
                                                          const int* __restrict__ rowptr,
                                                          const int* __restrict__ ssrc,
                                                          const int* __restrict__ gcnt,
                                                          const float* __restrict__ invd,
                                                          const u16* __restrict__ Wfrag,
                                                          const float* __restrict__ bias,
                                                          u16* __restrict__ hout, int n_nodes) {
    SAGE_PROLOGUE()

#pragma unroll
    for (int c = 0; c < 4; ++c) {
        int col = ch * 64 + c * 16 + m;
        float bc = bias[col];
#pragma unroll
        for (int r = 0; r < 4; ++r) {
            int n = n0 + rt * 16 + q * 4 + r;
            if (n < n_nodes)
                hout[(size_t)n * 128 + col] = f2bf(fmaxf(acc[c][r] + bc, 0.f));
        }
    }
}

// Fused final sage layer + layer-2 projection: h2 tile stays in LDS, never hits HBM.
// Writes Gn = h2 @ Wl2-frag (cols 0..47 of GSTRIDE rows) and Gs = h2 @ Wr2-frag.
__global__ __launch_bounds__(256, 8) void sage_layer_mfma_g(const uint2* __restrict__ hin2,
                                                            const int* __restrict__ rowptr,
                                                            const int* __restrict__ ssrc,
                                                            const int* __restrict__ gcnt,
                                                            const float* __restrict__ invd,
                                                            const u16* __restrict__ Wfrag,
                                                            const float* __restrict__ bias,
                                                            const u16* __restrict__ Wfrag2,
                                                            u16* __restrict__ Gn,
                                                            u16* __restrict__ Gs, int n_nodes) {
    SAGE_PROLOGUE()

    // stage-1 epilogue: relu+bias -> h2 tile back into As cols 0..127 (bf16)
    __syncthreads();  // all waves done reading As stage-1 fragments
#pragma unroll
    for (int c = 0; c < 4; ++c) {
        int col = ch * 64 + c * 16 + m;
        float bc = bias[col];
#pragma unroll
        for (int r = 0; r < 4; ++r) {
            int row = rt * 16 + q * 4 + r;
            As[row][col] = f2bf(fmaxf(acc[c][r] + bc, 0.f));
        }
    }
    __syncthreads();

    // stage 2: [Gn|Gs] = h2 @ Wfrag2, K=128
    f4v acc2[4];
#pragma unroll
    for (int c = 0; c < 4; ++c) acc2[c] = (f4v){0.f, 0.f, 0.f, 0.f};
#pragma unroll
    for (int kt = 0; kt < 4; ++kt) {
        s8v a = *(const s8v*)&As[rt * 16 + m][kt * 32 + q * 8];
#pragma unroll
        for (int c = 0; c < 4; ++c) {
            int ctg = ch * 4 + c;
            s8v b = *(const s8v*)&Wfrag2[(((size_t)kt * 8 + ctg) * 64 + lane) * 8];
            acc2[c] = __builtin_amdgcn_mfma_f32_16x16x32_bf16(a, b, acc2[c], 0, 0, 0);
        }
    }

    // only cols 0..47 are kept (47 classes + 1 pad col), GSTRIDE=48 rows
    u16* Gbase = (ch == 0) ? Gn : Gs;
#pragma unroll
    for (int c = 0; c < 3; ++c) {
        int col = c * 16 + m;
#pragma unroll
        for (int r = 0; r < 4; ++r) {
            int n = n0 + rt * 16 + q * 4 + r;
            if (n < n_nodes) Gbase[(size_t)n * GSTRIDE + col] = f2bf(acc2[c][r]);
        }
    }
}

// ---------------- layer-2 epilogue: gather Gn (96 B rows) + log_softmax ----------------
// Sage-shaped (R11, −22 us): 32 nodes/block, eloc LDS index staging, 16-lane groups
// each own one node pulled from an LDS rowctr; 4 edges in flight per group batch.
__global__ __launch_bounds__(256) void out_kernel(const u16* __restrict__ Gn,
                                                  const u16* __restrict__ Gs,
                                                  const int* __restrict__ rowptr,
                                                  const int* __restrict__ ssrc,
                                                  const int* __restrict__ gcnt,
                                                  const float* __restrict__ inv_deg,
                                                  const float* __restrict__ bias,
                                                  float* __restrict__ out, int n_nodes) {
    __shared__ int eloc[MAX_BE];
    __shared__ int rp[33];
    __shared__ int rowctr;
    int tid = threadIdx.x;
    int n0 = blockIdx.x * 32;
    if (tid < 33) rp[tid] = rowptr[min(n0 + tid, n_nodes)];
    if (tid == 0) rowctr = 0;
    __syncthreads();
    int bkt = n0 >> BUCKET_SHIFT;
    int bend = bkt * BCAP + min(gcnt[bkt], BCAP);
    int base = rp[0];
    int nE = min(rp[32], bend) - base;
    bool staged = nE <= MAX_BE;
    if (staged) {
        for (int i = tid; i < nE; i += 256) eloc[i] = ssrc[base + i];
    }
    __syncthreads();

    int lane = tid & 63;
    int t = lane & 15;            // uint2 column within row (cols 4t..4t+3)
    bool act = t < 12;
    int tcl = min(t, 11);         // clamped: lanes 12..15 duplicate lane 11's load
    const uint2* Gn2 = (const uint2*)Gn;   // row = 12 uint2 (96 B)

    while (true) {
        int row = 0;
        if (t == 0) row = atomicAdd(&rowctr, 1);
        row = __shfl(row, lane & 48, 64);   // broadcast from group leader (lane 0/16/32/48)
        if (row >= 32) break;
        int n = n0 + row;
        if (n >= n_nodes) continue;          // tail block: skip, pull next
        int e0 = rp[row] - base, e1 = min(rp[row + 1], bend) - base;
        float id = inv_deg[n];
        uint2 gs = ((const uint2*)Gs)[(size_t)n * 12 + tcl];
        float f0 = 0.f, f1 = 0.f, f2 = 0.f, f3 = 0.f;
        if (staged) {
            for (int e = e0; e < e1; e += 4) {
                int s[4];
                float mk[4];
#pragma unroll
                for (int j = 0; j < 4; ++j) {
                    int ix = e + j;
                    mk[j] = (ix < e1) ? 1.f : 0.f;
                    s[j] = eloc[min(ix, e1 - 1)];   // e<e1 in body: e1-1 >= e0 safe
                }
                uint2 g[4];
#pragma unroll
                for (int j = 0; j < 4; ++j) g[j] = Gn2[(size_t)s[j] * 12 + tcl];
#pragma unroll
                for (int j = 0; j < 4; ++j) {
                    f0 = fmaf(mk[j], blo(g[j].x), f0); f1 = fmaf(mk[j], bhi(g[j].x), f1);
                    f2 = fmaf(mk[j], blo(g[j].y), f2); f3 = fmaf(mk[j], bhi(g[j].y), f3);
                }
            }
        } else {
            for (int e = e0; e < e1; e += 4) {
                int s[4];
                float mk[4];
#pragma unroll
                for (int j = 0; j < 4; ++j) {
                    int ix = e + j;
                    mk[j] = (ix < e1) ? 1.f : 0.f;
                    s[j] = ssrc[base + min(ix, e1 - 1)];
                }
                uint2 g[4];
#pragma unroll
                for (int j = 0; j < 4; ++j) g[j] = Gn2[(size_t)s[j] * 12 + tcl];
#pragma unroll
                for (int j = 0; j < 4; ++j) {
                    f0 = fmaf(mk[j], blo(g[j].x), f0); f1 = fmaf(mk[j], bhi(g[j].x), f1);
                    f2 = fmaf(mk[j], blo(g[j].y), f2); f3 = fmaf(mk[j], bhi(g[j].y), f3);
                }
            }
        }

        int c0 = 4 * t;
        float v0 = (act && c0 + 0 < 47) ? f0 * id + blo(gs.x) + bias[c0 + 0] : -INFINITY;
        float v1 = (act && c0 + 1 < 47) ? f1 * id + bhi(gs.x) + bias[c0 + 1] : -INFINITY;
        float v2 = (act && c0 + 2 < 47) ? f2 * id + blo(gs.y) + bias[c0 + 2] : -INFINITY;
        float v3 = (act && c0 + 3 < 47) ? f3 * id + bhi(gs.y) + bias[c0 + 3] : -INFINITY;

        // softmax across the 16-lane group (each group owns one node)
        float m = fmaxf(fmaxf(v0, v1), fmaxf(v2, v3));
#pragma unroll
        for (int off = 8; off >= 1; off >>= 1)
            m = fmaxf(m, __shfl_xor(m, off, 16));
        float s = ((v0 != -INFINITY) ? __expf(v0 - m) : 0.f) +
                  ((v1 != -INFINITY) ? __expf(v1 - m) : 0.f) +
                  ((v2 != -INFINITY) ? __expf(v2 - m) : 0.f) +
                  ((v3 != -INFINITY) ? __expf(v3 - m) : 0.f);
#pragma unroll
        for (int off = 8; off >= 1; off >>= 1)
            s += __shfl_xor(s, off, 16);
        float ls = __logf(s);
        if (act) {
            float* o = &out[(size_t)n * 47];
            if (c0 + 0 < 47) o[c0 + 0] = v0 - m - ls;
            if (c0 + 1 < 47) o[c0 + 1] = v1 - m - ls;
            if (c0 + 2 < 47) o[c0 + 2] = v2 - m - ls;
            if (c0 + 3 < 47) o[c0 + 3] = v3 - m - ls;
        }
    }
}

// ---------------- launch ----------------

extern "C" void kernel_launch(void* const* d_in, const int* in_sizes, int n_in,
                              void* d_out, int out_size, void* d_ws, size_t ws_size,
                              hipStream_t stream) {
    const float* x   = (const float*)d_in[0];
    const int*   src = (const int*)d_in[1];
    const int*   dst = (const int*)d_in[2];
    const float* Wl0 = (const float*)d_in[3];
    const float* bl0 = (const float*)d_in[4];
    const float* Wr0 = (const float*)d_in[5];
    const float* Wl1 = (const float*)d_in[6];
    const float* bl1 = (const float*)d_in[7];
    const float* Wr1 = (const float*)d_in[8];
    const float* Wl2 = (const float*)d_in[9];
    const float* bl2 = (const float*)d_in[10];
    const float* Wr2 = (const float*)d_in[11];
    float* out = (float*)d_out;

    int N = in_sizes[0] / 128;
    int E = in_sizes[1];
    int nBuckets = (N + 255) >> BUCKET_SHIFT;

    char* ws = (char*)d_ws;
    size_t off = 0;
    auto alloc = [&](size_t bytes) -> char* {
        char* p = ws + off;
        off += (bytes + 255) & ~(size_t)255;
        return p;
    };
    int*   rowptr = (int*)alloc((size_t)(N + 1) * 4);
    float* invd   = (float*)alloc((size_t)N * 4);
    int*   ssrc   = (int*)alloc((size_t)nBuckets * BCAP * 4);  // bucket-strided
    u16*   xb     = (u16*)alloc((size_t)N * 128 * 2);   // layer0 in, layer1 out
    u16*   h1     = (u16*)alloc((size_t)N * 128 * 2);   // layer0 out, layer1 in
    u16*   Gn     = (u16*)alloc((size_t)N * GSTRIDE * 2);  // neighbor projection (layer 2)
    u16*   Gs     = (u16*)alloc((size_t)N * GSTRIDE * 2);  // self projection (layer 2)
    int*   gcur   = (int*)alloc(512 * 4);
    u16*   wf0    = (u16*)alloc(32768 * 2);
    u16*   wf1    = (u16*)alloc(32768 * 2);
    u16*   wf2    = (u16*)alloc(16384 * 2);

    // interm (nBuckets*BCAP uints = 7.2 MB) aliases Gn+Gs (19.2 MB): consumed by
    // bucket_build long before sage_layer_mfma_g writes Gn/Gs.
    unsigned* interm = (unsigned*)Gn;

    int nChunks = (E + CHUNK - 1) / CHUNK;
    long total8 = (long)N * 16;  // N*128/8
    int convBlocks = (int)((total8 + 255) / 256);

    hipMemsetAsync(gcur, 0, 512 * 4, stream);
    scatter_fat_kernel<<<nChunks + 320 + convBlocks, 256, 0, stream>>>(
        src, dst, gcur, interm, E, nBuckets,
        x, xb, total8, Wl0, Wr0, Wl1, Wr1, Wl2, Wr2, wf0, wf1, wf2, nChunks);
    bucket_build_kernel<<<nBuckets, 256, 0, stream>>>(interm, gcur, rowptr, invd, ssrc, N);

    int gemmGrid = (N + 31) / 32;

    // layer 0: xb -> h1 (fused gather-agg + MFMA)
    sage_layer_mfma<<<gemmGrid, 256, 0, stream>>>((const uint2*)xb, rowptr, ssrc, gcur,
                                                  invd, wf0, bl0, h1, N);
    // layer 1 + layer-2 projection fused: h1 -> [Gn|Gs], h2 never hits HBM
    sage_layer_mfma_g<<<gemmGrid, 256, 0, stream>>>((const uint2*)h1, rowptr, ssrc, gcur,
                                                    invd, wf1, bl1, wf2, Gn, Gs, N);
    // layer 2 epilogue: 96 B line gather + log_softmax (sage-shaped, 32 nodes/block)
    out_kernel<<<gemmGrid, 256, 0, stream>>>(Gn, Gs, rowptr, ssrc, gcur, invd, bl2,
                                             out, N);
}

// Round 13
// 335.914 us; speedup vs baseline: 1.0191x; 1.0191x over previous
//
#include <hip/hip_runtime.h>
#include <math.h>

#define BUCKET_SHIFT 8  // 256 nodes per bucket
#define MAX_BE 832      // max staged edges per block (block edge count ~ Poisson(512), 14 sigma)
#define CHUNK 4096      // edges per CSR-build chunk (391 blocks: better CU coverage)
#define GSTRIDE 48      // Gn/Gs row stride (47 cols used; 96 B rows, -25% vs 64)
#define BCAP 4608       // fixed per-bucket edge capacity (mean 4096, +8 sigma)

typedef short s8v __attribute__((ext_vector_type(8)));   // 8 bf16 (4 VGPRs)
typedef float f4v __attribute__((ext_vector_type(4)));   // 4 fp32 acc
typedef unsigned short u16;

__device__ inline u16 f2bf(float f) {  // RNE fp32->bf16
    unsigned u = __float_as_uint(f);
    return (u16)((u + 0x7FFFu + ((u >> 16) & 1u)) >> 16);
}
__device__ inline float bf2f(u16 s) { return __uint_as_float(((unsigned)s) << 16); }
__device__ inline float blo(unsigned v) { return __uint_as_float(v << 16); }
__device__ inline float bhi(unsigned v) { return __uint_as_float(v & 0xffff0000u); }

// ---------------- CSR build (bucketed, fixed-capacity: no count/scan passes) ----------------
// Bucket j owns interm/ssrc region [j*BCAP, (j+1)*BCAP). The region's tail above the
// bucket's true edge count is UNINITIALIZED — every consumer must clamp row ends with
// bend = j*BCAP + min(gcnt[j], BCAP). (R5 crash: rowptr[n+1] of a bucket's last node
// points at the NEXT bucket's base; unclamped loops walked the gap -> OOB gather.)

__global__ __launch_bounds__(256) void bucket_scatter_kernel(const int* __restrict__ src,
                                                             const int* __restrict__ dst,
                                                             int* __restrict__ gcursor,
                                                             unsigned* __restrict__ interm,
                                                             int n_edges, int nbuckets) {
    __shared__ int hist[512];
    __shared__ int gbase[512];
    int tid = threadIdx.x;
    for (int j = tid; j < nbuckets; j += 256) hist[j] = 0;
    __syncthreads();
    int e0 = blockIdx.x * CHUNK;
    int e1 = min(e0 + CHUNK, n_edges);
    for (int e = e0 + tid; e < e1; e += 256)
        atomicAdd(&hist[dst[e] >> BUCKET_SHIFT], 1);
    __syncthreads();
    for (int j = tid; j < nbuckets; j += 256) {
        int c = hist[j];
        gbase[j] = j * BCAP + (c > 0 ? atomicAdd(&gcursor[j], c) : 0);
        hist[j] = 0;
    }
    __syncthreads();
    for (int e = e0 + tid; e < e1; e += 256) {
        int d = dst[e];
        int s = src[e];
        int j = d >> BUCKET_SHIFT;
        int p = atomicAdd(&hist[j], 1);
        int idx = gbase[j] + p;
        if (idx < (j + 1) * BCAP)  // 8-sigma safety: never cross into next bucket
            interm[idx] = ((unsigned)s << 8) | (unsigned)(d & 255);
    }
}

// Fat prep kernel: one dispatch replaces {bucket_build, convert, pack_all} (R8: −11 us
// from dispatch-overhead removal). Block ranges:
//   [0, nbuckets)                      -> bucket_build (one block per bucket)
//   [nbuckets, nbuckets+convBlocks)    -> x -> bf16 convert
//   [nbuckets+convBlocks, +320)        -> weight packing
__global__ __launch_bounds__(256) void prep_fat_kernel(
    const unsigned* __restrict__ interm, const int* __restrict__ gcursor,
    int* __restrict__ rowptr, float* __restrict__ invd, int* __restrict__ ssrc,
    const float* __restrict__ x, u16* __restrict__ xb, long total8,
    const float* __restrict__ Wl0, const float* __restrict__ Wr0,
    const float* __restrict__ Wl1, const float* __restrict__ Wr1,
    const float* __restrict__ Wl2, const float* __restrict__ Wr2,
    u16* __restrict__ wf0, u16* __restrict__ wf1, u16* __restrict__ wf2,
    int n_nodes, int nbuckets, int convBlocks) {
    int blk = blockIdx.x;
    int tid = threadIdx.x;

    if (blk < nbuckets) {
        __shared__ int cnt[256];
        __shared__ int cur[256];
        __shared__ int wsum[4], woff[4];
        int nb0 = blk << BUCKET_SHIFT;
        int base = blk * BCAP;
        int end = base + min(gcursor[blk], BCAP);
        cnt[tid] = 0;
        __syncthreads();
        for (int e = base + tid; e < end; e += 256)
            atomicAdd(&cnt[interm[e] & 255u], 1);
        __syncthreads();
        int c = cnt[tid];
        int lane = tid & 63, wave = tid >> 6;
        int v = c;
#pragma unroll
        for (int off = 1; off < 64; off <<= 1) {
            int t = __shfl_up(v, off, 64);
            if (lane >= off) v += t;
        }
        if (lane == 63) wsum[wave] = v;
        __syncthreads();
        if (tid == 0) {
            int run = 0;
#pragma unroll
            for (int w = 0; w < 4; ++w) { woff[w] = run; run += wsum[w]; }
        }
        __syncthreads();
        int excl = woff[wave] + (v - c);
        int node = nb0 + tid;
        if (node < n_nodes) {
            rowptr[node] = base + excl;
            invd[node] = c > 0 ? 1.0f / (float)c : 0.0f;
            if (node == n_nodes - 1) rowptr[n_nodes] = base + excl + c;
        }
        cur[tid] = base + excl;
        __syncthreads();
        for (int e = base + tid; e < end; e += 256) {
            unsigned p = interm[e];
            int pos = atomicAdd(&cur[p & 255u], 1);
            ssrc[pos] = (int)(p >> 8);
        }
    } else if (blk < nbuckets + convBlocks) {
        long i = (long)(blk - nbuckets) * 256 + tid;
        if (i >= total8) return;
        const float* p = &x[i * 8];
        float4 lo = *(const float4*)p;
        float4 hi = *(const float4*)(p + 4);
        union { u16 u[8]; s8v v; } t;
        t.u[0] = f2bf(lo.x); t.u[1] = f2bf(lo.y); t.u[2] = f2bf(lo.z); t.u[3] = f2bf(lo.w);
        t.u[4] = f2bf(hi.x); t.u[5] = f2bf(hi.y); t.u[6] = f2bf(hi.z); t.u[7] = f2bf(hi.w);
        *(s8v*)&xb[i * 8] = t.v;
    } else {
        int b = blk - nbuckets - convBlocks;  // 0..319
        if (b < 256) {
            const float* Wl = (b < 128) ? Wl0 : Wl1;
            const float* Wr = (b < 128) ? Wr0 : Wr1;
            u16* outw = (b < 128) ? wf0 : wf1;
            int idx = (b & 127) * 256 + tid;  // 256*128
            int k = idx >> 7, c = idx & 127;
            float v = (k < 128) ? Wl[k * 128 + c] : Wr[(k - 128) * 128 + c];
            int kt = k >> 5, q = (k >> 3) & 3, j = k & 7, ct = c >> 4, n = c & 15;
            outw[(((kt * 8 + ct) * 64 + q * 16 + n) << 3) + j] = f2bf(v);
        } else {
            int idx = (b - 256) * 256 + tid;  // 128*128
            int k = idx >> 7, c = idx & 127;
            float v = 0.f;
            if (c < 47) v = Wl2[k * 47 + c];
            else if (c >= 64 && c < 111) v = Wr2[k * 47 + (c - 64)];
            int kt = k >> 5, q = (k >> 3) & 3, j = k & 7, ct = c >> 4, n = c & 15;
            wf2[(((kt * 8 + ct) * 64 + q * 16 + n) << 3) + j] = f2bf(v);
        }
    }
}

// ---------------- fused SAGE layer: LDS edge staging -> gather-agg -> MFMA ----------------
// Gather: 32-lane groups pull row indices from an LDS atomic counter. Per row: 32
// lanes x uint2 (8 B) = one full 256 B feature row per load instruction, 8 edges
// unrolled (4 KB in flight / wave).
// R2 lesson: do NOT split lanes across multiple edges — more concurrent unique rows
// thrashes L2 (FETCH +23%, WRITE 4x).
// R5 lesson: bucket-strided ssrc has an uninitialized gap at each bucket tail; all
// row ends MUST be clamped to bend.
// R9 lesson: KEEP eloc LDS index staging even though each index is consumed once —
// it breaks the index-load -> gather-load dependency chain (removal cost +7.7 us/sage).
// R12 lesson: hoisting self-row loads into registers does NOT prefetch (compiler sinks
// them back); keep the simple post-gather staging loop.
// LDS: As 16896 B + eloc 3328 B + rp 132 B + rowctr -> 20480 -> 8 blocks/CU
// (exactly 160 KiB LDS and the 2048-thread/CU cap) = 32 waves/CU.
#define SAGE_PROLOGUE()                                                                   \
    __shared__ u16 As[32][264];                                                           \
    __shared__ int eloc[MAX_BE];                                                          \
    __shared__ int rp[33];                                                                \
    __shared__ int rowctr;                                                                \
    int tid = threadIdx.x;                                                                \
    int n0 = blockIdx.x * 32;                                                             \
    if (tid < 33) rp[tid] = rowptr[min(n0 + tid, n_nodes)];                               \
    if (tid == 0) rowctr = 0;                                                             \
    __syncthreads();                                                                      \
    int bkt = n0 >> BUCKET_SHIFT;                                                         \
    int bend = bkt * BCAP + min(gcnt[bkt], BCAP);                                         \
    int base = rp[0];                                                                     \
    int nE = min(rp[32], bend) - base;                                                    \
    bool staged = nE <= MAX_BE;                                                           \
    if (staged) {                                                                         \
        for (int i = tid; i < nE; i += 256) eloc[i] = ssrc[base + i];                     \
    }                                                                                     \
    __syncthreads();                                                                      \
    int d = tid & 31;                                                                     \
    while (true) {                                                                        \
        int row = 0;                                                                      \
        if (d == 0) row = atomicAdd(&rowctr, 1);                                          \
        row = __shfl(row, 0, 32);                                                         \
        if (row >= 32) break;                                                             \
        int n = n0 + row;                                                                 \
        float a0 = 0.f, a1 = 0.f, a2 = 0.f, a3 = 0.f;                                     \
        int e = rp[row] - base, e1 = min(rp[row + 1], bend) - base;                       \
        if (staged) {                                                                     \
            for (; e + 7 < e1; e += 8) {                                                  \
                int s[8];                                                                 \
                _Pragma("unroll")                                                         \
                for (int j = 0; j < 8; ++j) s[j] = eloc[e + j];                           \
                uint2 vv[8];                                                              \
                _Pragma("unroll")                                                         \
                for (int j = 0; j < 8; ++j) vv[j] = hin2[(size_t)s[j] * 32 + d];          \
                _Pragma("unroll")                                                         \
                for (int j = 0; j < 8; ++j) {                                             \
                    a0 += blo(vv[j].x); a1 += bhi(vv[j].x);                               \
                    a2 += blo(vv[j].y); a3 += bhi(vv[j].y);                               \
                }                                                                         \
            }                                                                             \
            for (; e < e1; ++e) {                                                         \
                uint2 vv = hin2[(size_t)eloc[e] * 32 + d];                                \
                a0 += blo(vv.x); a1 += bhi(vv.x);                                         \
                a2 += blo(vv.y); a3 += bhi(vv.y);                                         \
            }                                                                             \
        } else {                                                                          \
            for (; e + 7 < e1; e += 8) {                                                  \
                int s[8];                                                                 \
                _Pragma("unroll")                                                         \
                for (int j = 0; j < 8; ++j) s[j] = ssrc[base + e + j];                    \
                uint2 vv[8];                                                              \
                _Pragma("unroll")                                                         \
                for (int j = 0; j < 8; ++j) vv[j] = hin2[(size_t)s[j] * 32 + d];          \
                _Pragma("unroll")                                                         \
                for (int j = 0; j < 8; ++j) {                                             \
                    a0 += blo(vv[j].x); a1 += bhi(vv[j].x);                               \
                    a2 += blo(vv[j].y); a3 += bhi(vv[j].y);                               \
                }                                                                         \
            }                                                                             \
            for (; e < e1; ++e) {                                                         \
                uint2 vv = hin2[(size_t)ssrc[base + e] * 32 + d];                         \
                a0 += blo(vv.x); a1 += bhi(vv.x);                                         \
                a2 += blo(vv.y); a3 += bhi(vv.y);                                         \
            }                                                                             \
        }                                                                                 \
        float w = (n < n_nodes) ? invd[n] : 0.f;                                          \
        a0 *= w; a1 *= w; a2 *= w; a3 *= w;                                               \
        uint2 o;                                                                          \
        o.x = (unsigned)f2bf(a0) | ((unsigned)f2bf(a1) << 16);                            \
        o.y = (unsigned)f2bf(a2) | ((unsigned)f2bf(a3) << 16);                            \
        *(uint2*)&As[row][d * 4] = o;                                                     \
    }                                                                                     \
    const u16* hin = (const u16*)hin2;                                                    \
    for (int i = tid; i < 512; i += 256) {                                                \
        int row = i >> 4, c8 = i & 15;                                                    \
        int n = n0 + row;                                                                 \
        s8v t = (s8v){0, 0, 0, 0, 0, 0, 0, 0};                                            \
        if (n < n_nodes) t = *(const s8v*)&hin[(size_t)n * 128 + c8 * 8];                 \
        *(s8v*)&As[row][128 + c8 * 8] = t;                                                \
    }                                                                                     \
    __syncthreads();                                                                      \
    int wave = tid >> 6, lane = tid & 63;                                                 \
    int rt = wave & 1, ch = wave >> 1;                                                    \
    int m = lane & 15, q = lane >> 4;                                                     \
    f4v acc[4];                                                                           \
    _Pragma("unroll")                                                                     \
    for (int c = 0; c < 4; ++c) acc[c] = (f4v){0.f, 0.f, 0.f, 0.f};                       \
    _Pragma("unroll")                                                                     \
    for (int kt = 0; kt < 8; ++kt) {                                                      \
        s8v a = *(const s8v*)&As[rt * 16 + m][kt * 32 + q * 8];                           \
        _Pragma("unroll")                                                                 \
        for (int c = 0; c < 4; ++c) {                                                     \
            int ctg = ch * 4 + c;                                                         \
            s8v b = *(const s8v*)&Wfrag[(((size_t)kt * 8 + ctg) * 64 + lane) * 8];        \
            acc[c] = __builtin_amdgcn_mfma_f32_16x16x32_bf16(a, b, acc[c], 0, 0, 0);      \
        }                                                                                 \
    }

// hout = relu([mean_agg(hin) | hin] @ Wfrag + b). hin/hout distinct buffers.
__global__ __launch_bounds__(256, 8) void sage_layer_mfma(const uint2* __restrict__ hin2,
                                                          const int* __restrict__ rowptr,
                                                          const int* __restrict__ ssrc,
                                                          const int* __restrict__ gcnt,
                                                          const float* __restrict__ invd,
                                                          const u16* __restrict__ Wfrag,
                                                          const float* __restrict__ bias,
                                                          u16* __restrict__ hout, int n_nodes) {
    SAGE_PROLOGUE()

#pragma unroll
    for (int c = 0; c < 4; ++c) {
        int col = ch * 64 + c * 16 + m;
        float bc = bias[col];
#pragma unroll
        for (int r = 0; r < 4; ++r) {
            int n = n0 + rt * 16 + q * 4 + r;
            if (n < n_nodes)
                hout[(size_t)n * 128 + col] = f2bf(fmaxf(acc[c][r] + bc, 0.f));
        }
    }
}

// Fused final sage layer + layer-2 projection: h2 tile stays in LDS, never hits HBM.
// Writes Gn = h2 @ Wl2-frag (cols 0..47 of GSTRIDE rows) and Gs = h2 @ Wr2-frag.
__global__ __launch_bounds__(256, 8) void sage_layer_mfma_g(const uint2* __restrict__ hin2,
                                                            const int* __restrict__ rowptr,
                                                            const int* __restrict__ ssrc,
                                                            const int* __restrict__ gcnt,
                                                            const float* __restrict__ invd,
                                                            const u16* __restrict__ Wfrag,
                                                            const float* __restrict__ bias,
                                                            const u16* __restrict__ Wfrag2,
                                                            u16* __restrict__ Gn,
                                                            u16* __restrict__ Gs, int n_nodes) {
    SAGE_PROLOGUE()

    // stage-1 epilogue: relu+bias -> h2 tile back into As cols 0..127 (bf16)
    __syncthreads();  // all waves done reading As stage-1 fragments
#pragma unroll
    for (int c = 0; c < 4; ++c) {
        int col = ch * 64 + c * 16 + m;
        float bc = bias[col];
#pragma unroll
        for (int r = 0; r < 4; ++r) {
            int row = rt * 16 + q * 4 + r;
            As[row][col] = f2bf(fmaxf(acc[c][r] + bc, 0.f));
        }
    }
    __syncthreads();

    // stage 2: [Gn|Gs] = h2 @ Wfrag2, K=128
    f4v acc2[4];
#pragma unroll
    for (int c = 0; c < 4; ++c) acc2[c] = (f4v){0.f, 0.f, 0.f, 0.f};
#pragma unroll
    for (int kt = 0; kt < 4; ++kt) {
        s8v a = *(const s8v*)&As[rt * 16 + m][kt * 32 + q * 8];
#pragma unroll
        for (int c = 0; c < 4; ++c) {
            int ctg = ch * 4 + c;
            s8v b = *(const s8v*)&Wfrag2[(((size_t)kt * 8 + ctg) * 64 + lane) * 8];
            acc2[c] = __builtin_amdgcn_mfma_f32_16x16x32_bf16(a, b, acc2[c], 0, 0, 0);
        }
    }

    // only cols 0..47 are kept (47 classes + 1 pad col), GSTRIDE=48 rows
    u16* Gbase = (ch == 0) ? Gn : Gs;
#pragma unroll
    for (int c = 0; c < 3; ++c) {
        int col = c * 16 + m;
#pragma unroll
        for (int r = 0; r < 4; ++r) {
            int n = n0 + rt * 16 + q * 4 + r;
            if (n < n_nodes) Gbase[(size_t)n * GSTRIDE + col] = f2bf(acc2[c][r]);
        }
    }
}

// ---------------- layer-2 epilogue: gather Gn (96 B rows) + log_softmax ----------------
// Sage-shaped (R11, −22 us): 32 nodes/block, eloc LDS index staging, 16-lane groups
// each own one node pulled from an LDS rowctr; 4 edges in flight per group batch.
__global__ __launch_bounds__(256) void out_kernel(const u16* __restrict__ Gn,
                                                  const u16* __restrict__ Gs,
                                                  const int* __restrict__ rowptr,
                                                  const int* __restrict__ ssrc,
                                                  const int* __restrict__ gcnt,
                                                  const float* __restrict__ inv_deg,
                                                  const float* __restrict__ bias,
                                                  float* __restrict__ out, int n_nodes) {
    __shared__ int eloc[MAX_BE];
    __shared__ int rp[33];
    __shared__ int rowctr;
    int tid = threadIdx.x;
    int n0 = blockIdx.x * 32;
    if (tid < 33) rp[tid] = rowptr[min(n0 + tid, n_nodes)];
    if (tid == 0) rowctr = 0;
    __syncthreads();
    int bkt = n0 >> BUCKET_SHIFT;
    int bend = bkt * BCAP + min(gcnt[bkt], BCAP);
    int base = rp[0];
    int nE = min(rp[32], bend) - base;
    bool staged = nE <= MAX_BE;
    if (staged) {
        for (int i = tid; i < nE; i += 256) eloc[i] = ssrc[base + i];
    }
    __syncthreads();

    int lane = tid & 63;
    int t = lane & 15;            // uint2 column within row (cols 4t..4t+3)
    bool act = t < 12;
    int tcl = min(t, 11);         // clamped: lanes 12..15 duplicate lane 11's load
    const uint2* Gn2 = (const uint2*)Gn;   // row = 12 uint2 (96 B)

    while (true) {
        int row = 0;
        if (t == 0) row = atomicAdd(&rowctr, 1);
        row = __shfl(row, lane & 48, 64);   // broadcast from group leader (lane 0/16/32/48)
        if (row >= 32) break;
        int n = n0 + row;
        if (n >= n_nodes) continue;          // tail block: skip, pull next
        int e0 = rp[row] - base, e1 = min(rp[row + 1], bend) - base;
        float id = inv_deg[n];
        uint2 gs = ((const uint2*)Gs)[(size_t)n * 12 + tcl];
        float f0 = 0.f, f1 = 0.f, f2 = 0.f, f3 = 0.f;
        if (staged) {
            for (int e = e0; e < e1; e += 4) {
                int s[4];
                float mk[4];
#pragma unroll
                for (int j = 0; j < 4; ++j) {
                    int ix = e + j;
                    mk[j] = (ix < e1) ? 1.f : 0.f;
                    s[j] = eloc[min(ix, e1 - 1)];   // e<e1 in body: e1-1 >= e0 safe
                }
                uint2 g[4];
#pragma unroll
                for (int j = 0; j < 4; ++j) g[j] = Gn2[(size_t)s[j] * 12 + tcl];
#pragma unroll
                for (int j = 0; j < 4; ++j) {
                    f0 = fmaf(mk[j], blo(g[j].x), f0); f1 = fmaf(mk[j], bhi(g[j].x), f1);
                    f2 = fmaf(mk[j], blo(g[j].y), f2); f3 = fmaf(mk[j], bhi(g[j].y), f3);
                }
            }
        } else {
            for (int e = e0; e < e1; e += 4) {
                int s[4];
                float mk[4];
#pragma unroll
                for (int j = 0; j < 4; ++j) {
                    int ix = e + j;
                    mk[j] = (ix < e1) ? 1.f : 0.f;
                    s[j] = ssrc[base + min(ix, e1 - 1)];
                }
                uint2 g[4];
#pragma unroll
                for (int j = 0; j < 4; ++j) g[j] = Gn2[(size_t)s[j] * 12 + tcl];
#pragma unroll
                for (int j = 0; j < 4; ++j) {
                    f0 = fmaf(mk[j], blo(g[j].x), f0); f1 = fmaf(mk[j], bhi(g[j].x), f1);
                    f2 = fmaf(mk[j], blo(g[j].y), f2); f3 = fmaf(mk[j], bhi(g[j].y), f3);
                }
            }
        }

        int c0 = 4 * t;
        float v0 = (act && c0 + 0 < 47) ? f0 * id + blo(gs.x) + bias[c0 + 0] : -INFINITY;
        float v1 = (act && c0 + 1 < 47) ? f1 * id + bhi(gs.x) + bias[c0 + 1] : -INFINITY;
        float v2 = (act && c0 + 2 < 47) ? f2 * id + blo(gs.y) + bias[c0 + 2] : -INFINITY;
        float v3 = (act && c0 + 3 < 47) ? f3 * id + bhi(gs.y) + bias[c0 + 3] : -INFINITY;

        // softmax across the 16-lane group (each group owns one node)
        float m = fmaxf(fmaxf(v0, v1), fmaxf(v2, v3));
#pragma unroll
        for (int off = 8; off >= 1; off >>= 1)
            m = fmaxf(m, __shfl_xor(m, off, 16));
        float s = ((v0 != -INFINITY) ? __expf(v0 - m) : 0.f) +
                  ((v1 != -INFINITY) ? __expf(v1 - m) : 0.f) +
                  ((v2 != -INFINITY) ? __expf(v2 - m) : 0.f) +
                  ((v3 != -INFINITY) ? __expf(v3 - m) : 0.f);
#pragma unroll
        for (int off = 8; off >= 1; off >>= 1)
            s += __shfl_xor(s, off, 16);
        float ls = __logf(s);
        if (act) {
            float* o = &out[(size_t)n * 47];
            if (c0 + 0 < 47) o[c0 + 0] = v0 - m - ls;
            if (c0 + 1 < 47) o[c0 + 1] = v1 - m - ls;
            if (c0 + 2 < 47) o[c0 + 2] = v2 - m - ls;
            if (c0 + 3 < 47) o[c0 + 3] = v3 - m - ls;
        }
    }
}

// ---------------- launch ----------------

extern "C" void kernel_launch(void* const* d_in, const int* in_sizes, int n_in,
                              void* d_out, int out_size, void* d_ws, size_t ws_size,
                              hipStream_t stream) {
    const float* x   = (const float*)d_in[0];
    const int*   src = (const int*)d_in[1];
    const int*   dst = (const int*)d_in[2];
    const float* Wl0 = (const float*)d_in[3];
    const float* bl0 = (const float*)d_in[4];
    const float* Wr0 = (const float*)d_in[5];
    const float* Wl1 = (const float*)d_in[6];
    const float* bl1 = (const float*)d_in[7];
    const float* Wr1 = (const float*)d_in[8];
    const float* Wl2 = (const float*)d_in[9];
    const float* bl2 = (const float*)d_in[10];
    const float* Wr2 = (const float*)d_in[11];
    float* out = (float*)d_out;

    int N = in_sizes[0] / 128;
    int E = in_sizes[1];
    int nBuckets = (N + 255) >> BUCKET_SHIFT;

    char* ws = (char*)d_ws;
    size_t off = 0;
    auto alloc = [&](size_t bytes) -> char* {
        char* p = ws + off;
        off += (bytes + 255) & ~(size_t)255;
        return p;
    };
    int*   rowptr = (int*)alloc((size_t)(N + 1) * 4);
    float* invd   = (float*)alloc((size_t)N * 4);
    int*   ssrc   = (int*)alloc((size_t)nBuckets * BCAP * 4);  // bucket-strided
    u16*   xb     = (u16*)alloc((size_t)N * 128 * 2);   // layer0 in, layer1 out
    u16*   h1     = (u16*)alloc((size_t)N * 128 * 2);   // layer0 out, layer1 in
    u16*   Gn     = (u16*)alloc((size_t)N * GSTRIDE * 2);  // neighbor projection (layer 2)
    u16*   Gs     = (u16*)alloc((size_t)N * GSTRIDE * 2);  // self projection (layer 2)
    int*   gcur   = (int*)alloc(512 * 4);
    u16*   wf0    = (u16*)alloc(32768 * 2);
    u16*   wf1    = (u16*)alloc(32768 * 2);
    u16*   wf2    = (u16*)alloc(16384 * 2);

    // interm (nBuckets*BCAP uints = 7.2 MB) aliases Gn+Gs (19.2 MB): consumed by
    // prep_fat's build branch long before sage_layer_mfma_g writes Gn/Gs.
    unsigned* interm = (unsigned*)Gn;

    int nChunks = (E + CHUNK - 1) / CHUNK;
    long total8 = (long)N * 16;  // N*128/8
    int convBlocks = (int)((total8 + 255) / 256);

    hipMemsetAsync(gcur, 0, 512 * 4, stream);
    bucket_scatter_kernel<<<nChunks, 256, 0, stream>>>(src, dst, gcur, interm, E, nBuckets);
    prep_fat_kernel<<<nBuckets + convBlocks + 320, 256, 0, stream>>>(
        interm, gcur, rowptr, invd, ssrc, x, xb, total8,
        Wl0, Wr0, Wl1, Wr1, Wl2, Wr2, wf0, wf1, wf2, N, nBuckets, convBlocks);

    int gemmGrid = (N + 31) / 32;

    // layer 0: xb -> h1 (fused gather-agg + MFMA)
    sage_layer_mfma<<<gemmGrid, 256, 0, stream>>>((const uint2*)xb, rowptr, ssrc, gcur,
                                                  invd, wf0, bl0, h1, N);
    // layer 1 + layer-2 projection fused: h1 -> [Gn|Gs], h2 never hits HBM
    sage_layer_mfma_g<<<gemmGrid, 256, 0, stream>>>((const uint2*)h1, rowptr, ssrc, gcur,
                                                    invd, wf1, bl1, wf2, Gn, Gs, N);
    // layer 2 epilogue: 96 B line gather + log_softmax (sage-shaped, 32 nodes/block)
    out_kernel<<<gemmGrid, 256, 0, stream>>>(Gn, Gs, rowptr, ssrc, gcur, invd, bl2,
                                             out, N);
}